// Round 6
// baseline (293.715 us; speedup 1.0000x reference)
//
#include <hip/hip_runtime.h>
#include <math.h>

// GCN 2-layer on MI355X. N=100000, E=3200000, F_IN=256, HID=32, F_OUT=64.
// CSR build: radix by 256-node coarse bucket (write-combined reserved runs,
// packed row<<8|col8), then per-bucket 2-pass counting sort into an
// L2-resident 32KB window -> per-node CSR (erow) + dinv. Aggregations are
// CSR gathers (float4 lanes, 4-wide unroll). No global float atomics.
// dinv folded into source: agg(h)[i] = dinv[i]*(sum_{j->i} g[j] + g[i]), g = dinv.h

#define SHIFT1 8
#define S1 256
#define MAXNB1 400

__device__ inline float4 add4(float4 a, float4 b) {
    return make_float4(a.x + b.x, a.y + b.y, a.z + b.z, a.w + b.w);
}

__global__ void k_zero(int* p, int n) {
    int i = blockIdx.x * blockDim.x + threadIdx.x;
    if (i < n) p[i] = 0;
}

// coarse bucket counts, int4-vectorized, per-block LDS histogram
__global__ void k_hist1(const int4* __restrict__ cols4, int* __restrict__ bcnt,
                        int e4, int etail, const int* __restrict__ cols, int nb) {
    __shared__ int h[MAXNB1];
    for (int i = threadIdx.x; i < nb; i += blockDim.x) h[i] = 0;
    __syncthreads();
    for (int i = blockIdx.x * blockDim.x + threadIdx.x; i < e4; i += gridDim.x * blockDim.x) {
        int4 c = cols4[i];
        atomicAdd(&h[c.x >> SHIFT1], 1);
        atomicAdd(&h[c.y >> SHIFT1], 1);
        atomicAdd(&h[c.z >> SHIFT1], 1);
        atomicAdd(&h[c.w >> SHIFT1], 1);
    }
    if (blockIdx.x == 0 && threadIdx.x < etail)
        atomicAdd(&h[cols[e4 * 4 + threadIdx.x] >> SHIFT1], 1);
    __syncthreads();
    for (int i = threadIdx.x; i < nb; i += blockDim.x)
        if (h[i]) atomicAdd(&bcnt[i], h[i]);
}

// exclusive scan of nb (<=512) bucket counts
__global__ void k_scan1(const int* __restrict__ bcnt, int* __restrict__ bptr,
                        int* __restrict__ bfill, int nb, int e) {
    __shared__ int sh[512];
    int tid = threadIdx.x;
    int v = (tid < nb) ? bcnt[tid] : 0;
    sh[tid] = v;
    __syncthreads();
    for (int off = 1; off < 512; off <<= 1) {
        int t = (tid >= off) ? sh[tid - off] : 0;
        __syncthreads();
        sh[tid] += t;
        __syncthreads();
    }
    int excl = sh[tid] - v;
    if (tid < nb) { bptr[tid] = excl; bfill[tid] = excl; }
    if (tid == 0) bptr[nb] = e;
}

// bucket the edges, packed (row<<8)|(col&255); per-block reservation ->
// ~800B sequential runs per bucket, block write footprint ~100KB (L2-resident)
__global__ void k_scatter1(const int* __restrict__ rows, const int* __restrict__ cols,
                           int* bfill, unsigned* __restrict__ pk, int e, int nb, int chunk) {
    __shared__ int hist[MAXNB1];
    int tid = threadIdx.x;
    for (int i = tid; i < nb; i += blockDim.x) hist[i] = 0;
    __syncthreads();
    int start = blockIdx.x * chunk;
    int end = min(e, start + chunk);
    for (int i = start + tid; i < end; i += blockDim.x)
        atomicAdd(&hist[cols[i] >> SHIFT1], 1);
    __syncthreads();
    for (int i = tid; i < nb; i += blockDim.x) {
        int c = hist[i];
        if (c) hist[i] = atomicAdd(&bfill[i], c);   // hist[] becomes per-block base
    }
    __syncthreads();
    for (int i = start + tid; i < end; i += blockDim.x) {
        int r = rows[i], c = cols[i];
        int pos = atomicAdd(&hist[c >> SHIFT1], 1);
        pk[pos] = ((unsigned)r << SHIFT1) | (unsigned)(c & (S1 - 1));
    }
}

// per-bucket counting sort (2 passes over an 8K-edge range): histogram ->
// scan -> scatter erow into the bucket's own 32KB window (L2-local).
// Emits per-node CSR ptr + dinv. No capacity limit.
__launch_bounds__(256)
__global__ void k_fine256(const unsigned* __restrict__ pk, const int* __restrict__ bptr,
                          int* __restrict__ erow, int* __restrict__ ptr,
                          float* __restrict__ dinv, int n, int nb) {
    __shared__ int cnt[S1], sh[S1], fill[S1];
    int tid = threadIdx.x, b = blockIdx.x;
    cnt[tid] = 0;
    __syncthreads();
    int s = bptr[b], e = bptr[b + 1];
    for (int t = s + tid; t < e; t += 256)
        atomicAdd(&cnt[pk[t] & (S1 - 1)], 1);
    __syncthreads();
    int v = cnt[tid];
    sh[tid] = v;
    __syncthreads();
    for (int off = 1; off < 256; off <<= 1) {
        int t = (tid >= off) ? sh[tid - off] : 0;
        __syncthreads();
        sh[tid] += t;
        __syncthreads();
    }
    int base = sh[tid] - v;
    fill[tid] = base;
    int node = (b << SHIFT1) + tid;
    if (node < n) {
        ptr[node] = s + base;
        dinv[node] = rsqrtf((float)(v + 1));
    }
    if (b == nb - 1 && tid == 0) ptr[n] = e;
    __syncthreads();
    for (int t = s + tid; t < e; t += 256) {
        unsigned p = pk[t];
        int pos = atomicAdd(&fill[p & (S1 - 1)], 1);
        erow[s + pos] = (int)(p >> SHIFT1);
    }
}

// g1 = dinv (.) (x @ W1): LDS-tiled (x tile AND W1 in LDS), 32 nodes/block.
__launch_bounds__(256)
__global__ void k_xw_g(const float4* __restrict__ x4, const float4* __restrict__ W1_4,
                       const float* __restrict__ dinv, float* __restrict__ g1, int n) {
    __shared__ float xs[32 * 260];
    __shared__ float w1s[256 * 32];
    int tid = threadIdx.x;
    int nb = blockIdx.x * 32;
#pragma unroll
    for (int t = 0; t < 8; ++t) {
        int idx = tid + t * 256;
        int row = idx >> 6, c4 = idx & 63;
        float4 v = (nb + row < n) ? x4[(size_t)(nb + row) * 64 + c4]
                                  : make_float4(0.f, 0.f, 0.f, 0.f);
        *reinterpret_cast<float4*>(&xs[row * 260 + c4 * 4]) = v;
        *reinterpret_cast<float4*>(&w1s[idx * 4]) = W1_4[idx];
    }
    __syncthreads();
    int row = tid >> 3, k4 = tid & 7;
    int node = nb + row;
    if (node >= n) return;
    float s0 = 0.f, s1 = 0.f, s2 = 0.f, s3 = 0.f;
#pragma unroll 4
    for (int i4 = 0; i4 < 64; ++i4) {
        float4 xv = *reinterpret_cast<const float4*>(&xs[row * 260 + i4 * 4]);
#pragma unroll
        for (int c = 0; c < 4; ++c) {
            float xc = c == 0 ? xv.x : c == 1 ? xv.y : c == 2 ? xv.z : xv.w;
            float4 w = *reinterpret_cast<const float4*>(&w1s[(i4 * 4 + c) * 32 + k4 * 4]);
            s0 = fmaf(xc, w.x, s0); s1 = fmaf(xc, w.y, s1);
            s2 = fmaf(xc, w.z, s2); s3 = fmaf(xc, w.w, s3);
        }
    }
    float d = dinv[node];
    *reinterpret_cast<float4*>(&g1[(size_t)node * 32 + k4 * 4]) =
        make_float4(d * s0, d * s1, d * s2, d * s3);
}

// layer-1 aggregate (CSR gather, float4 lanes, 4-wide): g2 = dinv.relu(dinv*(sum)+b1)
__launch_bounds__(256)
__global__ void k_agg1(const float4* __restrict__ g1_4, const int* __restrict__ erow,
                       const int* __restrict__ ptr, const float* __restrict__ dinv,
                       const float* __restrict__ b1, float4* __restrict__ g2_4, int n) {
    int tid = threadIdx.x;
    int g = tid >> 3, l = tid & 7;
    int node = blockIdx.x * 32 + g;
    if (node >= n) return;
    int s = ptr[node], e = ptr[node + 1];
    float4 a0 = g1_4[(size_t)node * 8 + l];   // self-loop
    float4 a1 = make_float4(0.f, 0.f, 0.f, 0.f), a2 = a1, a3 = a1;
    int t = s;
    for (; t + 3 < e; t += 4) {
        int r0 = erow[t], r1 = erow[t + 1], r2 = erow[t + 2], r3 = erow[t + 3];
        float4 v0 = g1_4[(size_t)r0 * 8 + l];
        float4 v1 = g1_4[(size_t)r1 * 8 + l];
        float4 v2 = g1_4[(size_t)r2 * 8 + l];
        float4 v3 = g1_4[(size_t)r3 * 8 + l];
        a0 = add4(a0, v0); a1 = add4(a1, v1); a2 = add4(a2, v2); a3 = add4(a3, v3);
    }
    for (; t < e; ++t) a0 = add4(a0, g1_4[(size_t)erow[t] * 8 + l]);
    float4 acc = add4(add4(a0, a1), add4(a2, a3));
    float d = dinv[node];
    float4 bb = *reinterpret_cast<const float4*>(&b1[l * 4]);
    float4 h;
    h.x = fmaxf(fmaf(d, acc.x, bb.x), 0.f) * d;
    h.y = fmaxf(fmaf(d, acc.y, bb.y), 0.f) * d;
    h.z = fmaxf(fmaf(d, acc.z, bb.z), 0.f) * d;
    h.w = fmaxf(fmaf(d, acc.w, bb.w), 0.f) * d;
    g2_4[(size_t)node * 8 + l] = h;
}

// layer-2 aggregate + fused W2 projection
__launch_bounds__(256)
__global__ void k_agg2(const float4* __restrict__ g2_4, const int* __restrict__ erow,
                       const int* __restrict__ ptr, const float* __restrict__ dinv,
                       const float* __restrict__ W2, const float* __restrict__ b2,
                       float* __restrict__ out, int n) {
    __shared__ float fr[32][33];
    __shared__ float w2s[32 * 64];
    int tid = threadIdx.x;
    for (int t = tid; t < 32 * 64; t += 256) w2s[t] = W2[t];
    int g = tid >> 3, l = tid & 7;
    int node = blockIdx.x * 32 + g;
    float4 v = make_float4(0.f, 0.f, 0.f, 0.f);
    if (node < n) {
        int s = ptr[node], e = ptr[node + 1];
        float4 a0 = g2_4[(size_t)node * 8 + l];
        float4 a1 = make_float4(0.f, 0.f, 0.f, 0.f), a2 = a1, a3 = a1;
        int t = s;
        for (; t + 3 < e; t += 4) {
            int r0 = erow[t], r1 = erow[t + 1], r2 = erow[t + 2], r3 = erow[t + 3];
            float4 v0 = g2_4[(size_t)r0 * 8 + l];
            float4 v1 = g2_4[(size_t)r1 * 8 + l];
            float4 v2 = g2_4[(size_t)r2 * 8 + l];
            float4 v3 = g2_4[(size_t)r3 * 8 + l];
            a0 = add4(a0, v0); a1 = add4(a1, v1); a2 = add4(a2, v2); a3 = add4(a3, v3);
        }
        for (; t < e; ++t) a0 = add4(a0, g2_4[(size_t)erow[t] * 8 + l]);
        float4 acc = add4(add4(a0, a1), add4(a2, a3));
        float d = dinv[node];
        v = make_float4(d * acc.x, d * acc.y, d * acc.z, d * acc.w);
    }
    fr[g][l * 4 + 0] = v.x;
    fr[g][l * 4 + 1] = v.y;
    fr[g][l * 4 + 2] = v.z;
    fr[g][l * 4 + 3] = v.w;
    __syncthreads();
    int j = tid & 63, mg = tid >> 6;
    for (int mm = 0; mm < 8; ++mm) {
        int m = mg * 8 + mm;
        int node2 = blockIdx.x * 32 + m;
        if (node2 >= n) continue;
        float sacc = b2[j];
#pragma unroll
        for (int i = 0; i < 32; ++i)
            sacc = fmaf(fr[m][i], w2s[i * 64 + j], sacc);
        out[(size_t)node2 * 64 + j] = sacc;
    }
}

extern "C" void kernel_launch(void* const* d_in, const int* in_sizes, int n_in,
                              void* d_out, int out_size, void* d_ws, size_t ws_size,
                              hipStream_t stream) {
    const float* x  = (const float*)d_in[0];
    const int*   ei = (const int*)d_in[1];
    const float* W1 = (const float*)d_in[2];
    const float* b1 = (const float*)d_in[3];
    const float* W2 = (const float*)d_in[4];
    const float* b2 = (const float*)d_in[5];
    float* out = (float*)d_out;

    const int N = in_sizes[0] / 256;
    const int E = in_sizes[1] / 2;
    const int* rows = ei;        // edge_index[0] (source)
    const int* cols = ei + E;    // edge_index[1] (dest)
    const int NB1 = (N + S1 - 1) >> SHIFT1;   // 391 coarse buckets

    // ws layout (4B units):
    // buf0 = pk[E] (CSR build) aliased with g1[N*32] (dead after k_fine256)
    // | erow[E] | g2[N*32] | dinv[N] | ptr[N+1] | bptr1[NB1+1] | bcnt1[NB1] | bfill1[NB1]
    size_t sz0 = (size_t)E > (size_t)N * 32 ? (size_t)E : (size_t)N * 32;
    unsigned* pk = (unsigned*)d_ws;
    float* g1    = (float*)d_ws;
    int*   erow  = (int*)((char*)d_ws + sz0 * 4);
    float* g2    = (float*)(erow + E);
    float* dinv  = g2 + (size_t)N * 32;
    int*   ptr   = (int*)(dinv + N);
    int*   bptr1 = ptr + (N + 1);
    int*   bcnt1 = bptr1 + (NB1 + 1);
    int*   bfill1= bcnt1 + NB1;

    const int B = 256;
    const int e4 = E / 4, etail = E - e4 * 4;
    const int chunk = (E + 127) / 128;
    const int nblk = (N + 31) / 32;

    k_zero<<<(NB1 + B - 1) / B, B, 0, stream>>>(bcnt1, NB1);
    k_hist1<<<256, B, 0, stream>>>((const int4*)cols, bcnt1, e4, etail, cols, NB1);
    k_scan1<<<1, 512, 0, stream>>>(bcnt1, bptr1, bfill1, NB1, E);
    k_scatter1<<<128, B, 0, stream>>>(rows, cols, bfill1, pk, E, NB1, chunk);
    k_fine256<<<NB1, B, 0, stream>>>(pk, bptr1, erow, ptr, dinv, N, NB1);
    k_xw_g<<<(N + 31) / 32, B, 0, stream>>>((const float4*)x, (const float4*)W1, dinv, g1, N);
    k_agg1<<<nblk, B, 0, stream>>>((const float4*)g1, erow, ptr, dinv, b1, (float4*)g2, N);
    k_agg2<<<nblk, B, 0, stream>>>((const float4*)g2, erow, ptr, dinv, W2, b2, out, N);
}

// Round 7
// 254.209 us; speedup vs baseline: 1.1554x; 1.1554x over previous
//
#include <hip/hip_runtime.h>
#include <math.h>

// GCN 2-layer on MI355X. N=100000, E=3200000, F_IN=256, HID=32, F_OUT=64.
// CSR build: radix by 256-node coarse bucket (write-combined reserved runs,
// packed row<<8|col8), then per-bucket 2-pass counting sort into an
// L2-resident 32KB window -> per-node CSR (erow) + dinv. Aggregations are
// CSR gathers (float4 lanes, 4-wide unroll). No global float atomics.
// dinv folded into source: agg(h)[i] = dinv[i]*(sum_{j->i} g[j] + g[i]), g = dinv.h

#define SHIFT1 8
#define S1 256
#define MAXNB1 400

__device__ inline float4 add4(float4 a, float4 b) {
    return make_float4(a.x + b.x, a.y + b.y, a.z + b.z, a.w + b.w);
}

__global__ void k_zero(int* p, int n) {
    int i = blockIdx.x * blockDim.x + threadIdx.x;
    if (i < n) p[i] = 0;
}

// coarse bucket counts, int4-vectorized, per-block LDS histogram
__global__ void k_hist1(const int4* __restrict__ cols4, int* __restrict__ bcnt,
                        int e4, int etail, const int* __restrict__ cols, int nb) {
    __shared__ int h[MAXNB1];
    for (int i = threadIdx.x; i < nb; i += blockDim.x) h[i] = 0;
    __syncthreads();
    for (int i = blockIdx.x * blockDim.x + threadIdx.x; i < e4; i += gridDim.x * blockDim.x) {
        int4 c = cols4[i];
        atomicAdd(&h[c.x >> SHIFT1], 1);
        atomicAdd(&h[c.y >> SHIFT1], 1);
        atomicAdd(&h[c.z >> SHIFT1], 1);
        atomicAdd(&h[c.w >> SHIFT1], 1);
    }
    if (blockIdx.x == 0 && threadIdx.x < etail)
        atomicAdd(&h[cols[e4 * 4 + threadIdx.x] >> SHIFT1], 1);
    __syncthreads();
    for (int i = threadIdx.x; i < nb; i += blockDim.x)
        if (h[i]) atomicAdd(&bcnt[i], h[i]);
}

// exclusive scan of nb (<=512) bucket counts
__global__ void k_scan1(const int* __restrict__ bcnt, int* __restrict__ bptr,
                        int* __restrict__ bfill, int nb, int e) {
    __shared__ int sh[512];
    int tid = threadIdx.x;
    int v = (tid < nb) ? bcnt[tid] : 0;
    sh[tid] = v;
    __syncthreads();
    for (int off = 1; off < 512; off <<= 1) {
        int t = (tid >= off) ? sh[tid - off] : 0;
        __syncthreads();
        sh[tid] += t;
        __syncthreads();
    }
    int excl = sh[tid] - v;
    if (tid < nb) { bptr[tid] = excl; bfill[tid] = excl; }
    if (tid == 0) bptr[nb] = e;
}

// bucket the edges, packed (row<<8)|(col&255); per-block reservation ->
// ~128B sequential runs per bucket, block write footprint ~50KB (L2-resident).
// 1024 threads x 256 blocks: enough waves/CU to hide latency.
__launch_bounds__(1024)
__global__ void k_scatter1(const int* __restrict__ rows, const int* __restrict__ cols,
                           int* bfill, unsigned* __restrict__ pk, int e, int nb, int chunk) {
    __shared__ int hist[MAXNB1];
    int tid = threadIdx.x;
    for (int i = tid; i < nb; i += blockDim.x) hist[i] = 0;
    __syncthreads();
    int start = blockIdx.x * chunk;
    int end = min(e, start + chunk);
    for (int i = start + tid; i < end; i += blockDim.x)
        atomicAdd(&hist[cols[i] >> SHIFT1], 1);
    __syncthreads();
    for (int i = tid; i < nb; i += blockDim.x) {
        int c = hist[i];
        if (c) hist[i] = atomicAdd(&bfill[i], c);   // hist[] becomes per-block base
    }
    __syncthreads();
    for (int i = start + tid; i < end; i += blockDim.x) {
        int r = rows[i], c = cols[i];
        int pos = atomicAdd(&hist[c >> SHIFT1], 1);
        pk[pos] = ((unsigned)r << SHIFT1) | (unsigned)(c & (S1 - 1));
    }
}

// per-bucket counting sort (2 passes over an 8K-edge range): histogram ->
// scan -> scatter erow into the bucket's own 32KB window (L2-local).
// Emits per-node CSR ptr + dinv. 512 threads for latency hiding.
__launch_bounds__(512)
__global__ void k_fine256(const unsigned* __restrict__ pk, const int* __restrict__ bptr,
                          int* __restrict__ erow, int* __restrict__ ptr,
                          float* __restrict__ dinv, int n, int nb) {
    __shared__ int cnt[S1], sh[S1], fill[S1];
    int tid = threadIdx.x, b = blockIdx.x;
    if (tid < S1) cnt[tid] = 0;
    __syncthreads();
    int s = bptr[b], e = bptr[b + 1];
    for (int t = s + tid; t < e; t += 512)
        atomicAdd(&cnt[pk[t] & (S1 - 1)], 1);
    __syncthreads();
    int v = (tid < S1) ? cnt[tid] : 0;
    if (tid < S1) sh[tid] = v;
    __syncthreads();
    for (int off = 1; off < S1; off <<= 1) {
        int t = (tid >= off && tid < S1) ? sh[tid - off] : 0;
        __syncthreads();
        if (tid < S1) sh[tid] += t;
        __syncthreads();
    }
    if (tid < S1) {
        int base = sh[tid] - v;
        fill[tid] = base;
        int node = (b << SHIFT1) + tid;
        if (node < n) {
            ptr[node] = s + base;
            dinv[node] = rsqrtf((float)(v + 1));
        }
    }
    if (b == nb - 1 && tid == 0) ptr[n] = e;
    __syncthreads();
    for (int t = s + tid; t < e; t += 512) {
        unsigned p = pk[t];
        int pos = atomicAdd(&fill[p & (S1 - 1)], 1);
        erow[s + pos] = (int)(p >> SHIFT1);
    }
}

// g1 = dinv (.) (x @ W1): LDS-tiled (x tile AND W1 in LDS), 32 nodes/block.
__launch_bounds__(256)
__global__ void k_xw_g(const float4* __restrict__ x4, const float4* __restrict__ W1_4,
                       const float* __restrict__ dinv, float* __restrict__ g1, int n) {
    __shared__ float xs[32 * 260];
    __shared__ float w1s[256 * 32];
    int tid = threadIdx.x;
    int nb = blockIdx.x * 32;
#pragma unroll
    for (int t = 0; t < 8; ++t) {
        int idx = tid + t * 256;
        int row = idx >> 6, c4 = idx & 63;
        float4 v = (nb + row < n) ? x4[(size_t)(nb + row) * 64 + c4]
                                  : make_float4(0.f, 0.f, 0.f, 0.f);
        *reinterpret_cast<float4*>(&xs[row * 260 + c4 * 4]) = v;
        *reinterpret_cast<float4*>(&w1s[idx * 4]) = W1_4[idx];
    }
    __syncthreads();
    int row = tid >> 3, k4 = tid & 7;
    int node = nb + row;
    if (node >= n) return;
    float s0 = 0.f, s1 = 0.f, s2 = 0.f, s3 = 0.f;
#pragma unroll 4
    for (int i4 = 0; i4 < 64; ++i4) {
        float4 xv = *reinterpret_cast<const float4*>(&xs[row * 260 + i4 * 4]);
#pragma unroll
        for (int c = 0; c < 4; ++c) {
            float xc = c == 0 ? xv.x : c == 1 ? xv.y : c == 2 ? xv.z : xv.w;
            float4 w = *reinterpret_cast<const float4*>(&w1s[(i4 * 4 + c) * 32 + k4 * 4]);
            s0 = fmaf(xc, w.x, s0); s1 = fmaf(xc, w.y, s1);
            s2 = fmaf(xc, w.z, s2); s3 = fmaf(xc, w.w, s3);
        }
    }
    float d = dinv[node];
    *reinterpret_cast<float4*>(&g1[(size_t)node * 32 + k4 * 4]) =
        make_float4(d * s0, d * s1, d * s2, d * s3);
}

// layer-1 aggregate (CSR gather, float4 lanes, 4-wide): g2 = dinv.relu(dinv*(sum)+b1)
__launch_bounds__(256)
__global__ void k_agg1(const float4* __restrict__ g1_4, const int* __restrict__ erow,
                       const int* __restrict__ ptr, const float* __restrict__ dinv,
                       const float* __restrict__ b1, float4* __restrict__ g2_4, int n) {
    int tid = threadIdx.x;
    int g = tid >> 3, l = tid & 7;
    int node = blockIdx.x * 32 + g;
    if (node >= n) return;
    int s = ptr[node], e = ptr[node + 1];
    float4 a0 = g1_4[(size_t)node * 8 + l];   // self-loop
    float4 a1 = make_float4(0.f, 0.f, 0.f, 0.f), a2 = a1, a3 = a1;
    int t = s;
    for (; t + 3 < e; t += 4) {
        int r0 = erow[t], r1 = erow[t + 1], r2 = erow[t + 2], r3 = erow[t + 3];
        float4 v0 = g1_4[(size_t)r0 * 8 + l];
        float4 v1 = g1_4[(size_t)r1 * 8 + l];
        float4 v2 = g1_4[(size_t)r2 * 8 + l];
        float4 v3 = g1_4[(size_t)r3 * 8 + l];
        a0 = add4(a0, v0); a1 = add4(a1, v1); a2 = add4(a2, v2); a3 = add4(a3, v3);
    }
    for (; t < e; ++t) a0 = add4(a0, g1_4[(size_t)erow[t] * 8 + l]);
    float4 acc = add4(add4(a0, a1), add4(a2, a3));
    float d = dinv[node];
    float4 bb = *reinterpret_cast<const float4*>(&b1[l * 4]);
    float4 h;
    h.x = fmaxf(fmaf(d, acc.x, bb.x), 0.f) * d;
    h.y = fmaxf(fmaf(d, acc.y, bb.y), 0.f) * d;
    h.z = fmaxf(fmaf(d, acc.z, bb.z), 0.f) * d;
    h.w = fmaxf(fmaf(d, acc.w, bb.w), 0.f) * d;
    g2_4[(size_t)node * 8 + l] = h;
}

// layer-2 aggregate + fused W2 projection
__launch_bounds__(256)
__global__ void k_agg2(const float4* __restrict__ g2_4, const int* __restrict__ erow,
                       const int* __restrict__ ptr, const float* __restrict__ dinv,
                       const float* __restrict__ W2, const float* __restrict__ b2,
                       float* __restrict__ out, int n) {
    __shared__ float fr[32][33];
    __shared__ float w2s[32 * 64];
    int tid = threadIdx.x;
    for (int t = tid; t < 32 * 64; t += 256) w2s[t] = W2[t];
    int g = tid >> 3, l = tid & 7;
    int node = blockIdx.x * 32 + g;
    float4 v = make_float4(0.f, 0.f, 0.f, 0.f);
    if (node < n) {
        int s = ptr[node], e = ptr[node + 1];
        float4 a0 = g2_4[(size_t)node * 8 + l];
        float4 a1 = make_float4(0.f, 0.f, 0.f, 0.f), a2 = a1, a3 = a1;
        int t = s;
        for (; t + 3 < e; t += 4) {
            int r0 = erow[t], r1 = erow[t + 1], r2 = erow[t + 2], r3 = erow[t + 3];
            float4 v0 = g2_4[(size_t)r0 * 8 + l];
            float4 v1 = g2_4[(size_t)r1 * 8 + l];
            float4 v2 = g2_4[(size_t)r2 * 8 + l];
            float4 v3 = g2_4[(size_t)r3 * 8 + l];
            a0 = add4(a0, v0); a1 = add4(a1, v1); a2 = add4(a2, v2); a3 = add4(a3, v3);
        }
        for (; t < e; ++t) a0 = add4(a0, g2_4[(size_t)erow[t] * 8 + l]);
        float4 acc = add4(add4(a0, a1), add4(a2, a3));
        float d = dinv[node];
        v = make_float4(d * acc.x, d * acc.y, d * acc.z, d * acc.w);
    }
    fr[g][l * 4 + 0] = v.x;
    fr[g][l * 4 + 1] = v.y;
    fr[g][l * 4 + 2] = v.z;
    fr[g][l * 4 + 3] = v.w;
    __syncthreads();
    int j = tid & 63, mg = tid >> 6;
    for (int mm = 0; mm < 8; ++mm) {
        int m = mg * 8 + mm;
        int node2 = blockIdx.x * 32 + m;
        if (node2 >= n) continue;
        float sacc = b2[j];
#pragma unroll
        for (int i = 0; i < 32; ++i)
            sacc = fmaf(fr[m][i], w2s[i * 64 + j], sacc);
        out[(size_t)node2 * 64 + j] = sacc;
    }
}

extern "C" void kernel_launch(void* const* d_in, const int* in_sizes, int n_in,
                              void* d_out, int out_size, void* d_ws, size_t ws_size,
                              hipStream_t stream) {
    const float* x  = (const float*)d_in[0];
    const int*   ei = (const int*)d_in[1];
    const float* W1 = (const float*)d_in[2];
    const float* b1 = (const float*)d_in[3];
    const float* W2 = (const float*)d_in[4];
    const float* b2 = (const float*)d_in[5];
    float* out = (float*)d_out;

    const int N = in_sizes[0] / 256;
    const int E = in_sizes[1] / 2;
    const int* rows = ei;        // edge_index[0] (source)
    const int* cols = ei + E;    // edge_index[1] (dest)
    const int NB1 = (N + S1 - 1) >> SHIFT1;   // 391 coarse buckets

    // ws layout (4B units):
    // buf0 = pk[E] (CSR build) aliased with g1[N*32] (dead after k_fine256)
    // | erow[E] | g2[N*32] | dinv[N] | ptr[N+1] | bptr1[NB1+1] | bcnt1[NB1] | bfill1[NB1]
    size_t sz0 = (size_t)E > (size_t)N * 32 ? (size_t)E : (size_t)N * 32;
    unsigned* pk = (unsigned*)d_ws;
    float* g1    = (float*)d_ws;
    int*   erow  = (int*)((char*)d_ws + sz0 * 4);
    float* g2    = (float*)(erow + E);
    float* dinv  = g2 + (size_t)N * 32;
    int*   ptr   = (int*)(dinv + N);
    int*   bptr1 = ptr + (N + 1);
    int*   bcnt1 = bptr1 + (NB1 + 1);
    int*   bfill1= bcnt1 + NB1;

    const int B = 256;
    const int e4 = E / 4, etail = E - e4 * 4;
    const int SCB = 256;                      // scatter blocks
    const int chunk = (E + SCB - 1) / SCB;    // 12500 edges/block
    const int nblk = (N + 31) / 32;

    k_zero<<<(NB1 + B - 1) / B, B, 0, stream>>>(bcnt1, NB1);
    k_hist1<<<256, B, 0, stream>>>((const int4*)cols, bcnt1, e4, etail, cols, NB1);
    k_scan1<<<1, 512, 0, stream>>>(bcnt1, bptr1, bfill1, NB1, E);
    k_scatter1<<<SCB, 1024, 0, stream>>>(rows, cols, bfill1, pk, E, NB1, chunk);
    k_fine256<<<NB1, 512, 0, stream>>>(pk, bptr1, erow, ptr, dinv, N, NB1);
    k_xw_g<<<(N + 31) / 32, B, 0, stream>>>((const float4*)x, (const float4*)W1, dinv, g1, N);
    k_agg1<<<nblk, B, 0, stream>>>((const float4*)g1, erow, ptr, dinv, b1, (float4*)g2, N);
    k_agg2<<<nblk, B, 0, stream>>>((const float4*)g2, erow, ptr, dinv, W2, b2, out, N);
}

// Round 8
// 225.984 us; speedup vs baseline: 1.2997x; 1.1249x over previous
//
#include <hip/hip_runtime.h>
#include <hip/hip_fp16.h>
#include <math.h>

// GCN 2-layer on MI355X. N=100000, E=3200000, F_IN=256, HID=32, F_OUT=64.
// CSR build: radix by 256-node coarse bucket (write-combined reserved runs,
// packed row<<8|col8), then per-bucket counting sort -> per-node CSR + dinv.
// Aggregations gather fp16 rows (64B) with f32 accumulation: 4 lanes/node,
// 16B/lane, 8-wide unroll => 16 rows per wave vmem instr, 8 loads in flight.
// dinv folded into source: agg(h)[i] = dinv[i]*(sum_{j->i} g[j] + g[i]), g = dinv.h

#define SHIFT1 8
#define S1 256
#define MAXNB1 400

__global__ void k_zero(int* p, int n) {
    int i = blockIdx.x * blockDim.x + threadIdx.x;
    if (i < n) p[i] = 0;
}

// coarse bucket counts, int4-vectorized, per-block LDS histogram
__global__ void k_hist1(const int4* __restrict__ cols4, int* __restrict__ bcnt,
                        int e4, int etail, const int* __restrict__ cols, int nb) {
    __shared__ int h[MAXNB1];
    for (int i = threadIdx.x; i < nb; i += blockDim.x) h[i] = 0;
    __syncthreads();
    for (int i = blockIdx.x * blockDim.x + threadIdx.x; i < e4; i += gridDim.x * blockDim.x) {
        int4 c = cols4[i];
        atomicAdd(&h[c.x >> SHIFT1], 1);
        atomicAdd(&h[c.y >> SHIFT1], 1);
        atomicAdd(&h[c.z >> SHIFT1], 1);
        atomicAdd(&h[c.w >> SHIFT1], 1);
    }
    if (blockIdx.x == 0 && threadIdx.x < etail)
        atomicAdd(&h[cols[e4 * 4 + threadIdx.x] >> SHIFT1], 1);
    __syncthreads();
    for (int i = threadIdx.x; i < nb; i += blockDim.x)
        if (h[i]) atomicAdd(&bcnt[i], h[i]);
}

// exclusive scan of nb (<=512) bucket counts
__global__ void k_scan1(const int* __restrict__ bcnt, int* __restrict__ bptr,
                        int* __restrict__ bfill, int nb, int e) {
    __shared__ int sh[512];
    int tid = threadIdx.x;
    int v = (tid < nb) ? bcnt[tid] : 0;
    sh[tid] = v;
    __syncthreads();
    for (int off = 1; off < 512; off <<= 1) {
        int t = (tid >= off) ? sh[tid - off] : 0;
        __syncthreads();
        sh[tid] += t;
        __syncthreads();
    }
    int excl = sh[tid] - v;
    if (tid < nb) { bptr[tid] = excl; bfill[tid] = excl; }
    if (tid == 0) bptr[nb] = e;
}

// bucket the edges, packed (row<<8)|(col&255); per-block reservation
__launch_bounds__(1024)
__global__ void k_scatter1(const int* __restrict__ rows, const int* __restrict__ cols,
                           int* bfill, unsigned* __restrict__ pk, int e, int nb, int chunk) {
    __shared__ int hist[MAXNB1];
    int tid = threadIdx.x;
    for (int i = tid; i < nb; i += blockDim.x) hist[i] = 0;
    __syncthreads();
    int start = blockIdx.x * chunk;
    int end = min(e, start + chunk);
    for (int i = start + tid; i < end; i += blockDim.x)
        atomicAdd(&hist[cols[i] >> SHIFT1], 1);
    __syncthreads();
    for (int i = tid; i < nb; i += blockDim.x) {
        int c = hist[i];
        if (c) hist[i] = atomicAdd(&bfill[i], c);
    }
    __syncthreads();
    for (int i = start + tid; i < end; i += blockDim.x) {
        int r = rows[i], c = cols[i];
        int pos = atomicAdd(&hist[c >> SHIFT1], 1);
        pk[pos] = ((unsigned)r << SHIFT1) | (unsigned)(c & (S1 - 1));
    }
}

// per-bucket counting sort -> erow + per-node CSR ptr + dinv
__launch_bounds__(512)
__global__ void k_fine256(const unsigned* __restrict__ pk, const int* __restrict__ bptr,
                          int* __restrict__ erow, int* __restrict__ ptr,
                          float* __restrict__ dinv, int n, int nb) {
    __shared__ int cnt[S1], sh[S1], fill[S1];
    int tid = threadIdx.x, b = blockIdx.x;
    if (tid < S1) cnt[tid] = 0;
    __syncthreads();
    int s = bptr[b], e = bptr[b + 1];
    for (int t = s + tid; t < e; t += 512)
        atomicAdd(&cnt[pk[t] & (S1 - 1)], 1);
    __syncthreads();
    int v = (tid < S1) ? cnt[tid] : 0;
    if (tid < S1) sh[tid] = v;
    __syncthreads();
    for (int off = 1; off < S1; off <<= 1) {
        int t = (tid >= off && tid < S1) ? sh[tid - off] : 0;
        __syncthreads();
        if (tid < S1) sh[tid] += t;
        __syncthreads();
    }
    if (tid < S1) {
        int base = sh[tid] - v;
        fill[tid] = base;
        int node = (b << SHIFT1) + tid;
        if (node < n) {
            ptr[node] = s + base;
            dinv[node] = rsqrtf((float)(v + 1));
        }
    }
    if (b == nb - 1 && tid == 0) ptr[n] = e;
    __syncthreads();
    for (int t = s + tid; t < e; t += 512) {
        unsigned p = pk[t];
        int pos = atomicAdd(&fill[p & (S1 - 1)], 1);
        erow[s + pos] = (int)(p >> SHIFT1);
    }
}

// accumulate 8 halves (one 16B load) into 8 f32 accumulators
__device__ inline void acc8(float* a, float4 q) {
    const __half2* h = reinterpret_cast<const __half2*>(&q);
#pragma unroll
    for (int i = 0; i < 4; ++i) {
        float2 f = __half22float2(h[i]);
        a[2 * i] += f.x; a[2 * i + 1] += f.y;
    }
}

// g1h = fp16( dinv (.) (x @ W1) ): LDS-tiled (x AND W1 in LDS), 32 nodes/block.
__launch_bounds__(256)
__global__ void k_xw_g(const float4* __restrict__ x4, const float4* __restrict__ W1_4,
                       const float* __restrict__ dinv, __half* __restrict__ g1h, int n) {
    __shared__ float xs[32 * 260];
    __shared__ float w1s[256 * 32];
    int tid = threadIdx.x;
    int nb = blockIdx.x * 32;
#pragma unroll
    for (int t = 0; t < 8; ++t) {
        int idx = tid + t * 256;
        int row = idx >> 6, c4 = idx & 63;
        float4 v = (nb + row < n) ? x4[(size_t)(nb + row) * 64 + c4]
                                  : make_float4(0.f, 0.f, 0.f, 0.f);
        *reinterpret_cast<float4*>(&xs[row * 260 + c4 * 4]) = v;
        *reinterpret_cast<float4*>(&w1s[idx * 4]) = W1_4[idx];
    }
    __syncthreads();
    int row = tid >> 3, k4 = tid & 7;
    int node = nb + row;
    if (node >= n) return;
    float s0 = 0.f, s1 = 0.f, s2 = 0.f, s3 = 0.f;
#pragma unroll 4
    for (int i4 = 0; i4 < 64; ++i4) {
        float4 xv = *reinterpret_cast<const float4*>(&xs[row * 260 + i4 * 4]);
#pragma unroll
        for (int c = 0; c < 4; ++c) {
            float xc = c == 0 ? xv.x : c == 1 ? xv.y : c == 2 ? xv.z : xv.w;
            float4 w = *reinterpret_cast<const float4*>(&w1s[(i4 * 4 + c) * 32 + k4 * 4]);
            s0 = fmaf(xc, w.x, s0); s1 = fmaf(xc, w.y, s1);
            s2 = fmaf(xc, w.z, s2); s3 = fmaf(xc, w.w, s3);
        }
    }
    float d = dinv[node];
    __half2 h0 = __floats2half2_rn(d * s0, d * s1);
    __half2 h1 = __floats2half2_rn(d * s2, d * s3);
    int2 pkw = make_int2(*(int*)&h0, *(int*)&h1);
    *reinterpret_cast<int2*>(&g1h[(size_t)node * 32 + k4 * 4]) = pkw;
}

// layer-1 aggregate (fp16 CSR gather, 4 lanes/node, 8-wide unroll):
// g2h = fp16( dinv (.) relu(dinv*(sum)+b1) )
__launch_bounds__(256)
__global__ void k_agg1(const float4* __restrict__ g1h4, const int* __restrict__ erow,
                       const int* __restrict__ ptr, const float* __restrict__ dinv,
                       const float* __restrict__ b1, int4* __restrict__ g2h4, int n) {
    int tid = threadIdx.x;
    int g = tid >> 2, l = tid & 3;
    int node = blockIdx.x * 64 + g;
    if (node >= n) return;
    int s = ptr[node], e = ptr[node + 1];
    float a[8] = {0, 0, 0, 0, 0, 0, 0, 0};
    float b[8] = {0, 0, 0, 0, 0, 0, 0, 0};
    acc8(a, g1h4[(size_t)node * 4 + l]);   // self-loop
    int t = s;
    for (; t + 7 < e; t += 8) {
        int r0 = erow[t],     r1 = erow[t + 1], r2 = erow[t + 2], r3 = erow[t + 3];
        int r4 = erow[t + 4], r5 = erow[t + 5], r6 = erow[t + 6], r7 = erow[t + 7];
        float4 q0 = g1h4[(size_t)r0 * 4 + l];
        float4 q1 = g1h4[(size_t)r1 * 4 + l];
        float4 q2 = g1h4[(size_t)r2 * 4 + l];
        float4 q3 = g1h4[(size_t)r3 * 4 + l];
        float4 q4 = g1h4[(size_t)r4 * 4 + l];
        float4 q5 = g1h4[(size_t)r5 * 4 + l];
        float4 q6 = g1h4[(size_t)r6 * 4 + l];
        float4 q7 = g1h4[(size_t)r7 * 4 + l];
        acc8(a, q0); acc8(b, q1); acc8(a, q2); acc8(b, q3);
        acc8(a, q4); acc8(b, q5); acc8(a, q6); acc8(b, q7);
    }
    for (; t < e; ++t) acc8(a, g1h4[(size_t)erow[t] * 4 + l]);
    float d = dinv[node];
    float4 bb0 = *reinterpret_cast<const float4*>(&b1[l * 8]);
    float4 bb1 = *reinterpret_cast<const float4*>(&b1[l * 8 + 4]);
    float o[8];
    const float* bbp = &bb0.x;
#pragma unroll
    for (int i = 0; i < 8; ++i) {
        float bi = i < 4 ? (&bb0.x)[i] : (&bb1.x)[i - 4];
        float h = fmaf(d, a[i] + b[i], bi);
        o[i] = (h > 0.f ? h : 0.f) * d;
    }
    (void)bbp;
    __half2 h0 = __floats2half2_rn(o[0], o[1]);
    __half2 h1 = __floats2half2_rn(o[2], o[3]);
    __half2 h2 = __floats2half2_rn(o[4], o[5]);
    __half2 h3 = __floats2half2_rn(o[6], o[7]);
    g2h4[(size_t)node * 4 + l] = make_int4(*(int*)&h0, *(int*)&h1, *(int*)&h2, *(int*)&h3);
}

// layer-2 aggregate (fp16 gather) + fused W2 projection (f32)
__launch_bounds__(256)
__global__ void k_agg2(const float4* __restrict__ g2h4, const int* __restrict__ erow,
                       const int* __restrict__ ptr, const float* __restrict__ dinv,
                       const float* __restrict__ W2, const float* __restrict__ b2,
                       float* __restrict__ out, int n) {
    __shared__ float fr[64][33];
    __shared__ float w2s[32 * 64];
    int tid = threadIdx.x;
    for (int t = tid; t < 32 * 64; t += 256) w2s[t] = W2[t];
    int g = tid >> 2, l = tid & 3;
    int node = blockIdx.x * 64 + g;
    float a[8] = {0, 0, 0, 0, 0, 0, 0, 0};
    float b[8] = {0, 0, 0, 0, 0, 0, 0, 0};
    float d = 0.f;
    if (node < n) {
        int s = ptr[node], e = ptr[node + 1];
        acc8(a, g2h4[(size_t)node * 4 + l]);   // self-loop
        int t = s;
        for (; t + 7 < e; t += 8) {
            int r0 = erow[t],     r1 = erow[t + 1], r2 = erow[t + 2], r3 = erow[t + 3];
            int r4 = erow[t + 4], r5 = erow[t + 5], r6 = erow[t + 6], r7 = erow[t + 7];
            float4 q0 = g2h4[(size_t)r0 * 4 + l];
            float4 q1 = g2h4[(size_t)r1 * 4 + l];
            float4 q2 = g2h4[(size_t)r2 * 4 + l];
            float4 q3 = g2h4[(size_t)r3 * 4 + l];
            float4 q4 = g2h4[(size_t)r4 * 4 + l];
            float4 q5 = g2h4[(size_t)r5 * 4 + l];
            float4 q6 = g2h4[(size_t)r6 * 4 + l];
            float4 q7 = g2h4[(size_t)r7 * 4 + l];
            acc8(a, q0); acc8(b, q1); acc8(a, q2); acc8(b, q3);
            acc8(a, q4); acc8(b, q5); acc8(a, q6); acc8(b, q7);
        }
        for (; t < e; ++t) acc8(a, g2h4[(size_t)erow[t] * 4 + l]);
        d = dinv[node];
    }
#pragma unroll
    for (int i = 0; i < 8; ++i) fr[g][l * 8 + i] = d * (a[i] + b[i]);
    __syncthreads();
    int j = tid & 63, mg = tid >> 6;   // 4 waves x 16 nodes each
    for (int mm = 0; mm < 16; ++mm) {
        int m = mg * 16 + mm;
        int node2 = blockIdx.x * 64 + m;
        if (node2 >= n) continue;
        float sacc = b2[j];
#pragma unroll
        for (int i = 0; i < 32; ++i)
            sacc = fmaf(fr[m][i], w2s[i * 64 + j], sacc);
        out[(size_t)node2 * 64 + j] = sacc;
    }
}

extern "C" void kernel_launch(void* const* d_in, const int* in_sizes, int n_in,
                              void* d_out, int out_size, void* d_ws, size_t ws_size,
                              hipStream_t stream) {
    const float* x  = (const float*)d_in[0];
    const int*   ei = (const int*)d_in[1];
    const float* W1 = (const float*)d_in[2];
    const float* b1 = (const float*)d_in[3];
    const float* W2 = (const float*)d_in[4];
    const float* b2 = (const float*)d_in[5];
    float* out = (float*)d_out;

    const int N = in_sizes[0] / 256;
    const int E = in_sizes[1] / 2;
    const int* rows = ei;        // edge_index[0] (source)
    const int* cols = ei + E;    // edge_index[1] (dest)
    const int NB1 = (N + S1 - 1) >> SHIFT1;   // 391 coarse buckets

    // ws layout (4B units):
    // buf0 = pk[E] (CSR build) aliased with g1h[N*16] (fp16, dead pk after fine)
    // | erow[E] | g2h[N*16] | dinv[N] | ptr[N+1] | bptr1 | bcnt1 | bfill1
    size_t sz0 = (size_t)E > (size_t)N * 16 ? (size_t)E : (size_t)N * 16;
    unsigned* pk  = (unsigned*)d_ws;
    __half*   g1h = (__half*)d_ws;
    int*      erow = (int*)((char*)d_ws + sz0 * 4);
    __half*   g2h  = (__half*)(erow + E);
    float*    dinv = (float*)((char*)(erow + E) + (size_t)N * 32 * 2);
    int*      ptr  = (int*)(dinv + N);
    int*      bptr1 = ptr + (N + 1);
    int*      bcnt1 = bptr1 + (NB1 + 1);
    int*      bfill1 = bcnt1 + NB1;

    const int B = 256;
    const int e4 = E / 4, etail = E - e4 * 4;
    const int SCB = 256;
    const int chunk = (E + SCB - 1) / SCB;
    const int nblk64 = (N + 63) / 64;

    k_zero<<<(NB1 + B - 1) / B, B, 0, stream>>>(bcnt1, NB1);
    k_hist1<<<256, B, 0, stream>>>((const int4*)cols, bcnt1, e4, etail, cols, NB1);
    k_scan1<<<1, 512, 0, stream>>>(bcnt1, bptr1, bfill1, NB1, E);
    k_scatter1<<<SCB, 1024, 0, stream>>>(rows, cols, bfill1, pk, E, NB1, chunk);
    k_fine256<<<NB1, 512, 0, stream>>>(pk, bptr1, erow, ptr, dinv, N, NB1);
    k_xw_g<<<(N + 31) / 32, B, 0, stream>>>((const float4*)x, (const float4*)W1, dinv, g1h, N);
    k_agg1<<<nblk64, B, 0, stream>>>((const float4*)g1h, erow, ptr, dinv, b1, (int4*)g2h, N);
    k_agg2<<<nblk64, B, 0, stream>>>((const float4*)g2h, erow, ptr, dinv, W2, b2, out, N);
}

// Round 9
// 203.792 us; speedup vs baseline: 1.4412x; 1.1089x over previous
//
#include <hip/hip_runtime.h>
#include <hip/hip_fp16.h>
#include <math.h>

// GCN 2-layer on MI355X. N=100000, E=3200000, F_IN=256, HID=32, F_OUT=64.
// CSR build: radix by 256-node coarse bucket (write-combined reserved runs,
// packed row<<8|col8), then per-bucket counting sort -> per-node CSR + dinv.
// x@W1 via MFMA fp16 (f32 accum): x and W1^T staged fp16 in LDS, 64x32 tile,
// mfma_f32_16x16x32_f16, C/D layout col=lane&15,row=(lane>>4)*4+reg (HW-verified).
// Aggregations gather fp16 rows (64B) with f32 accumulation: 4 lanes/node,
// 16B/lane, 8-wide unroll. dinv folded into source.

#define SHIFT1 8
#define S1 256
#define MAXNB1 400

typedef _Float16 half8 __attribute__((ext_vector_type(8)));
typedef float f32x4 __attribute__((ext_vector_type(4)));

__global__ void k_zero(int* p, int n) {
    int i = blockIdx.x * blockDim.x + threadIdx.x;
    if (i < n) p[i] = 0;
}

// coarse bucket counts, int4-vectorized, per-block LDS histogram
__global__ void k_hist1(const int4* __restrict__ cols4, int* __restrict__ bcnt,
                        int e4, int etail, const int* __restrict__ cols, int nb) {
    __shared__ int h[MAXNB1];
    for (int i = threadIdx.x; i < nb; i += blockDim.x) h[i] = 0;
    __syncthreads();
    for (int i = blockIdx.x * blockDim.x + threadIdx.x; i < e4; i += gridDim.x * blockDim.x) {
        int4 c = cols4[i];
        atomicAdd(&h[c.x >> SHIFT1], 1);
        atomicAdd(&h[c.y >> SHIFT1], 1);
        atomicAdd(&h[c.z >> SHIFT1], 1);
        atomicAdd(&h[c.w >> SHIFT1], 1);
    }
    if (blockIdx.x == 0 && threadIdx.x < etail)
        atomicAdd(&h[cols[e4 * 4 + threadIdx.x] >> SHIFT1], 1);
    __syncthreads();
    for (int i = threadIdx.x; i < nb; i += blockDim.x)
        if (h[i]) atomicAdd(&bcnt[i], h[i]);
}

// exclusive scan of nb (<=512) bucket counts
__global__ void k_scan1(const int* __restrict__ bcnt, int* __restrict__ bptr,
                        int* __restrict__ bfill, int nb, int e) {
    __shared__ int sh[512];
    int tid = threadIdx.x;
    int v = (tid < nb) ? bcnt[tid] : 0;
    sh[tid] = v;
    __syncthreads();
    for (int off = 1; off < 512; off <<= 1) {
        int t = (tid >= off) ? sh[tid - off] : 0;
        __syncthreads();
        sh[tid] += t;
        __syncthreads();
    }
    int excl = sh[tid] - v;
    if (tid < nb) { bptr[tid] = excl; bfill[tid] = excl; }
    if (tid == 0) bptr[nb] = e;
}

// bucket the edges, packed (row<<8)|(col&255); per-block reservation
__launch_bounds__(1024)
__global__ void k_scatter1(const int* __restrict__ rows, const int* __restrict__ cols,
                           int* bfill, unsigned* __restrict__ pk, int e, int nb, int chunk) {
    __shared__ int hist[MAXNB1];
    int tid = threadIdx.x;
    for (int i = tid; i < nb; i += blockDim.x) hist[i] = 0;
    __syncthreads();
    int start = blockIdx.x * chunk;
    int end = min(e, start + chunk);
    for (int i = start + tid; i < end; i += blockDim.x)
        atomicAdd(&hist[cols[i] >> SHIFT1], 1);
    __syncthreads();
    for (int i = tid; i < nb; i += blockDim.x) {
        int c = hist[i];
        if (c) hist[i] = atomicAdd(&bfill[i], c);
    }
    __syncthreads();
    for (int i = start + tid; i < end; i += blockDim.x) {
        int r = rows[i], c = cols[i];
        int pos = atomicAdd(&hist[c >> SHIFT1], 1);
        pk[pos] = ((unsigned)r << SHIFT1) | (unsigned)(c & (S1 - 1));
    }
}

// per-bucket counting sort -> erow + per-node CSR ptr + dinv
__launch_bounds__(512)
__global__ void k_fine256(const unsigned* __restrict__ pk, const int* __restrict__ bptr,
                          int* __restrict__ erow, int* __restrict__ ptr,
                          float* __restrict__ dinv, int n, int nb) {
    __shared__ int cnt[S1], sh[S1], fill[S1];
    int tid = threadIdx.x, b = blockIdx.x;
    if (tid < S1) cnt[tid] = 0;
    __syncthreads();
    int s = bptr[b], e = bptr[b + 1];
    for (int t = s + tid; t < e; t += 512)
        atomicAdd(&cnt[pk[t] & (S1 - 1)], 1);
    __syncthreads();
    int v = (tid < S1) ? cnt[tid] : 0;
    if (tid < S1) sh[tid] = v;
    __syncthreads();
    for (int off = 1; off < S1; off <<= 1) {
        int t = (tid >= off && tid < S1) ? sh[tid - off] : 0;
        __syncthreads();
        if (tid < S1) sh[tid] += t;
        __syncthreads();
    }
    if (tid < S1) {
        int base = sh[tid] - v;
        fill[tid] = base;
        int node = (b << SHIFT1) + tid;
        if (node < n) {
            ptr[node] = s + base;
            dinv[node] = rsqrtf((float)(v + 1));
        }
    }
    if (b == nb - 1 && tid == 0) ptr[n] = e;
    __syncthreads();
    for (int t = s + tid; t < e; t += 512) {
        unsigned p = pk[t];
        int pos = atomicAdd(&fill[p & (S1 - 1)], 1);
        erow[s + pos] = (int)(p >> SHIFT1);
    }
}

// g1h = fp16( dinv (.) (x @ W1) ) via MFMA: 64 nodes/block, 4 waves,
// each wave owns a 16-node M-tile and both 16-col N-tiles.
__launch_bounds__(256)
__global__ void k_xw_mfma(const float4* __restrict__ x4, const float4* __restrict__ W1_4,
                          const float* __restrict__ dinv, _Float16* __restrict__ g1h, int n) {
    __shared__ _Float16 xh[64][264];    // 33.8 KB, +8 pad: 2-way-conflict b128 reads
    __shared__ _Float16 w1t[32][264];   // 16.9 KB, W1 transposed [n][k]
    int tid = threadIdx.x;
    int base = blockIdx.x * 64;
#pragma unroll
    for (int t = 0; t < 16; ++t) {
        int idx = tid + t * 256;            // float4 idx in 64x64 tile
        int row = idx >> 6, c4 = idx & 63;
        float4 v = (base + row < n) ? x4[(size_t)(base + row) * 64 + c4]
                                    : make_float4(0.f, 0.f, 0.f, 0.f);
        __half2 a = __floats2half2_rn(v.x, v.y);
        __half2 b = __floats2half2_rn(v.z, v.w);
        *reinterpret_cast<int2*>(&xh[row][c4 * 4]) = make_int2(*(int*)&a, *(int*)&b);
    }
#pragma unroll
    for (int t = 0; t < 8; ++t) {
        int idx = tid + t * 256;            // float4 idx in 256x8 W1 grid
        int kk = idx >> 3, n4 = idx & 7;
        float4 w = W1_4[idx];
        w1t[n4 * 4 + 0][kk] = (_Float16)w.x;
        w1t[n4 * 4 + 1][kk] = (_Float16)w.y;
        w1t[n4 * 4 + 2][kk] = (_Float16)w.z;
        w1t[n4 * 4 + 3][kk] = (_Float16)w.w;
    }
    __syncthreads();
    int wid = tid >> 6, lane = tid & 63;
    int lrow = lane & 15, kgrp = lane >> 4;
    const _Float16* ap  = &xh[wid * 16 + lrow][kgrp * 8];
    const _Float16* bp0 = &w1t[lrow][kgrp * 8];
    const _Float16* bp1 = &w1t[16 + lrow][kgrp * 8];
    f32x4 acc0 = {0.f, 0.f, 0.f, 0.f}, acc1 = {0.f, 0.f, 0.f, 0.f};
#pragma unroll
    for (int kk = 0; kk < 8; ++kk) {
        half8 a  = *reinterpret_cast<const half8*>(ap + kk * 32);
        half8 b0 = *reinterpret_cast<const half8*>(bp0 + kk * 32);
        half8 b1 = *reinterpret_cast<const half8*>(bp1 + kk * 32);
        acc0 = __builtin_amdgcn_mfma_f32_16x16x32_f16(a, b0, acc0, 0, 0, 0);
        acc1 = __builtin_amdgcn_mfma_f32_16x16x32_f16(a, b1, acc1, 0, 0, 0);
    }
    // C/D: col = lane&15, row = (lane>>4)*4 + reg  [HW-verified]
#pragma unroll
    for (int r = 0; r < 4; ++r) {
        int node = base + wid * 16 + kgrp * 4 + r;
        if (node < n) {
            float d = dinv[node];
            g1h[(size_t)node * 32 + lrow]      = (_Float16)(acc0[r] * d);
            g1h[(size_t)node * 32 + 16 + lrow] = (_Float16)(acc1[r] * d);
        }
    }
}

// accumulate 8 halves (one 16B load) into 8 f32 accumulators
__device__ inline void acc8(float* a, float4 q) {
    const __half2* h = reinterpret_cast<const __half2*>(&q);
#pragma unroll
    for (int i = 0; i < 4; ++i) {
        float2 f = __half22float2(h[i]);
        a[2 * i] += f.x; a[2 * i + 1] += f.y;
    }
}

// layer-1 aggregate (fp16 CSR gather, 4 lanes/node, 8-wide unroll):
// g2h = fp16( dinv (.) relu(dinv*(sum)+b1) )
__launch_bounds__(256)
__global__ void k_agg1(const float4* __restrict__ g1h4, const int* __restrict__ erow,
                       const int* __restrict__ ptr, const float* __restrict__ dinv,
                       const float* __restrict__ b1, int4* __restrict__ g2h4, int n) {
    int tid = threadIdx.x;
    int g = tid >> 2, l = tid & 3;
    int node = blockIdx.x * 64 + g;
    if (node >= n) return;
    int s = ptr[node], e = ptr[node + 1];
    float a[8] = {0, 0, 0, 0, 0, 0, 0, 0};
    float b[8] = {0, 0, 0, 0, 0, 0, 0, 0};
    acc8(a, g1h4[(size_t)node * 4 + l]);   // self-loop
    int t = s;
    for (; t + 7 < e; t += 8) {
        int r0 = erow[t],     r1 = erow[t + 1], r2 = erow[t + 2], r3 = erow[t + 3];
        int r4 = erow[t + 4], r5 = erow[t + 5], r6 = erow[t + 6], r7 = erow[t + 7];
        float4 q0 = g1h4[(size_t)r0 * 4 + l];
        float4 q1 = g1h4[(size_t)r1 * 4 + l];
        float4 q2 = g1h4[(size_t)r2 * 4 + l];
        float4 q3 = g1h4[(size_t)r3 * 4 + l];
        float4 q4 = g1h4[(size_t)r4 * 4 + l];
        float4 q5 = g1h4[(size_t)r5 * 4 + l];
        float4 q6 = g1h4[(size_t)r6 * 4 + l];
        float4 q7 = g1h4[(size_t)r7 * 4 + l];
        acc8(a, q0); acc8(b, q1); acc8(a, q2); acc8(b, q3);
        acc8(a, q4); acc8(b, q5); acc8(a, q6); acc8(b, q7);
    }
    for (; t < e; ++t) acc8(a, g1h4[(size_t)erow[t] * 4 + l]);
    float d = dinv[node];
    float4 bb0 = *reinterpret_cast<const float4*>(&b1[l * 8]);
    float4 bb1 = *reinterpret_cast<const float4*>(&b1[l * 8 + 4]);
    float o[8];
#pragma unroll
    for (int i = 0; i < 8; ++i) {
        float bi = i < 4 ? (&bb0.x)[i] : (&bb1.x)[i - 4];
        float h = fmaf(d, a[i] + b[i], bi);
        o[i] = (h > 0.f ? h : 0.f) * d;
    }
    __half2 h0 = __floats2half2_rn(o[0], o[1]);
    __half2 h1 = __floats2half2_rn(o[2], o[3]);
    __half2 h2 = __floats2half2_rn(o[4], o[5]);
    __half2 h3 = __floats2half2_rn(o[6], o[7]);
    g2h4[(size_t)node * 4 + l] = make_int4(*(int*)&h0, *(int*)&h1, *(int*)&h2, *(int*)&h3);
}

// layer-2 aggregate (fp16 gather) + fused W2 projection (f32)
__launch_bounds__(256)
__global__ void k_agg2(const float4* __restrict__ g2h4, const int* __restrict__ erow,
                       const int* __restrict__ ptr, const float* __restrict__ dinv,
                       const float* __restrict__ W2, const float* __restrict__ b2,
                       float* __restrict__ out, int n) {
    __shared__ float fr[64][33];
    __shared__ float w2s[32 * 64];
    int tid = threadIdx.x;
    for (int t = tid; t < 32 * 64; t += 256) w2s[t] = W2[t];
    int g = tid >> 2, l = tid & 3;
    int node = blockIdx.x * 64 + g;
    float a[8] = {0, 0, 0, 0, 0, 0, 0, 0};
    float b[8] = {0, 0, 0, 0, 0, 0, 0, 0};
    float d = 0.f;
    if (node < n) {
        int s = ptr[node], e = ptr[node + 1];
        acc8(a, g2h4[(size_t)node * 4 + l]);   // self-loop
        int t = s;
        for (; t + 7 < e; t += 8) {
            int r0 = erow[t],     r1 = erow[t + 1], r2 = erow[t + 2], r3 = erow[t + 3];
            int r4 = erow[t + 4], r5 = erow[t + 5], r6 = erow[t + 6], r7 = erow[t + 7];
            float4 q0 = g2h4[(size_t)r0 * 4 + l];
            float4 q1 = g2h4[(size_t)r1 * 4 + l];
            float4 q2 = g2h4[(size_t)r2 * 4 + l];
            float4 q3 = g2h4[(size_t)r3 * 4 + l];
            float4 q4 = g2h4[(size_t)r4 * 4 + l];
            float4 q5 = g2h4[(size_t)r5 * 4 + l];
            float4 q6 = g2h4[(size_t)r6 * 4 + l];
            float4 q7 = g2h4[(size_t)r7 * 4 + l];
            acc8(a, q0); acc8(b, q1); acc8(a, q2); acc8(b, q3);
            acc8(a, q4); acc8(b, q5); acc8(a, q6); acc8(b, q7);
        }
        for (; t < e; ++t) acc8(a, g2h4[(size_t)erow[t] * 4 + l]);
        d = dinv[node];
    }
#pragma unroll
    for (int i = 0; i < 8; ++i) fr[g][l * 8 + i] = d * (a[i] + b[i]);
    __syncthreads();
    int j = tid & 63, mg = tid >> 6;   // 4 waves x 16 nodes each
    for (int mm = 0; mm < 16; ++mm) {
        int m = mg * 16 + mm;
        int node2 = blockIdx.x * 64 + m;
        if (node2 >= n) continue;
        float sacc = b2[j];
#pragma unroll
        for (int i = 0; i < 32; ++i)
            sacc = fmaf(fr[m][i], w2s[i * 64 + j], sacc);
        out[(size_t)node2 * 64 + j] = sacc;
    }
}

extern "C" void kernel_launch(void* const* d_in, const int* in_sizes, int n_in,
                              void* d_out, int out_size, void* d_ws, size_t ws_size,
                              hipStream_t stream) {
    const float* x  = (const float*)d_in[0];
    const int*   ei = (const int*)d_in[1];
    const float* W1 = (const float*)d_in[2];
    const float* b1 = (const float*)d_in[3];
    const float* W2 = (const float*)d_in[4];
    const float* b2 = (const float*)d_in[5];
    float* out = (float*)d_out;

    const int N = in_sizes[0] / 256;
    const int E = in_sizes[1] / 2;
    const int* rows = ei;        // edge_index[0] (source)
    const int* cols = ei + E;    // edge_index[1] (dest)
    const int NB1 = (N + S1 - 1) >> SHIFT1;   // 391 coarse buckets

    // ws layout (4B units):
    // buf0 = pk[E] (CSR build) aliased with g1h[N*32 halves] (dead pk after fine)
    // | erow[E] | g2h[N*32 halves] | dinv[N] | ptr[N+1] | bptr1 | bcnt1 | bfill1
    size_t sz0 = (size_t)E > (size_t)N * 16 ? (size_t)E : (size_t)N * 16;
    unsigned* pk  = (unsigned*)d_ws;
    _Float16* g1h = (_Float16*)d_ws;
    int*      erow = (int*)((char*)d_ws + sz0 * 4);
    _Float16* g2h  = (_Float16*)(erow + E);
    float*    dinv = (float*)((char*)(erow + E) + (size_t)N * 32 * 2);
    int*      ptr  = (int*)(dinv + N);
    int*      bptr1 = ptr + (N + 1);
    int*      bcnt1 = bptr1 + (NB1 + 1);
    int*      bfill1 = bcnt1 + NB1;

    const int B = 256;
    const int e4 = E / 4, etail = E - e4 * 4;
    const int SCB = 256;
    const int chunk = (E + SCB - 1) / SCB;
    const int nblk64 = (N + 63) / 64;

    k_zero<<<(NB1 + B - 1) / B, B, 0, stream>>>(bcnt1, NB1);
    k_hist1<<<256, B, 0, stream>>>((const int4*)cols, bcnt1, e4, etail, cols, NB1);
    k_scan1<<<1, 512, 0, stream>>>(bcnt1, bptr1, bfill1, NB1, E);
    k_scatter1<<<SCB, 1024, 0, stream>>>(rows, cols, bfill1, pk, E, NB1, chunk);
    k_fine256<<<NB1, 512, 0, stream>>>(pk, bptr1, erow, ptr, dinv, N, NB1);
    k_xw_mfma<<<nblk64, B, 0, stream>>>((const float4*)x, (const float4*)W1, dinv, g1h, N);
    k_agg1<<<nblk64, B, 0, stream>>>((const float4*)g1h, erow, ptr, dinv, b1, (int4*)g2h, N);
    k_agg2<<<nblk64, B, 0, stream>>>((const float4*)g2h, erow, ptr, dinv, W2, b2, out, N);
}